// Round 1
// baseline (758.990 us; speedup 1.0000x reference)
//
#include <hip/hip_runtime.h>
#include <hip/hip_bf16.h>

typedef __attribute__((ext_vector_type(4))) float f32x4;
typedef __attribute__((ext_vector_type(8))) short bf16x8;

#define HW 3136
#define NSEG 49            // 3136 / 64 pixel-tiles per sample
#define NELF 802816.0f     // 256*3136 elements per sample for all GN stats
#define EPS 1e-5f

__device__ __forceinline__ float geluf(float x) {
  return 0.5f * x * (1.0f + erff(x * 0.70710678118654752440f));
}
__device__ __forceinline__ short f2bf(float f) {
  union { float f; unsigned u; } v; v.f = f;
  unsigned r = (v.u + 0x7FFFu + ((v.u >> 16) & 1u)) >> 16;
  return (short)r;
}
__device__ __forceinline__ float b2f(unsigned short u) {
  union { unsigned u; float f; } v; v.u = ((unsigned)u) << 16;
  return v.f;
}
__device__ __forceinline__ bf16x8 pack8(float4 a, float4 b) {
  bf16x8 r;
  r[0] = f2bf(a.x); r[1] = f2bf(a.y); r[2] = f2bf(a.z); r[3] = f2bf(a.w);
  r[4] = f2bf(b.x); r[5] = f2bf(b.y); r[6] = f2bf(b.z); r[7] = f2bf(b.w);
  return r;
}

// K0: per-sample sum / sumsq of x
__global__ void stats_kernel(const float* __restrict__ x, float* __restrict__ st) {
  int b = blockIdx.x, t = threadIdx.x;
  int n = b / NSEG, seg = b % NSEG;
  const float* p = x + (size_t)n * 802816 + (size_t)seg * 16384;
  float s = 0.f, q = 0.f;
#pragma unroll
  for (int i = 0; i < 16; ++i) {
    float4 v = *(const float4*)(p + (size_t)(t + i * 256) * 4);
    s += v.x + v.y + v.z + v.w;
    q += v.x * v.x + v.y * v.y + v.z * v.z + v.w * v.w;
  }
  __shared__ float r[512];
  r[t] = s; r[256 + t] = q;
  __syncthreads();
  for (int off = 128; off > 0; off >>= 1) {
    if (t < off) { r[t] += r[t + off]; r[256 + t] += r[256 + t + off]; }
    __syncthreads();
  }
  if (t == 0) { atomicAdd(&st[n * 2], r[0]); atomicAdd(&st[n * 2 + 1], r[256]); }
}

// PRO: 0 = gn(f32 act); 1 = shift_w + gn + gelu; 2 = shift_h + gn + gelu; 3 = bf16 passthrough
// EPI: 0 = store f32 + stats; 1 = store gelu f32; 2 = rmw-add gelu + stats;
//      3 = +resid store + stats; 4 = store gelu bf16; 5 = +resid store f32
template<int PRO, int EPI, int KTOT, int OTOT>
__global__ __launch_bounds__(256) void gemm_kernel(
    const float* __restrict__ act, const unsigned short* __restrict__ act_bf,
    const float* __restrict__ Wt, const float* __restrict__ bias,
    const float* __restrict__ gw, const float* __restrict__ gb,
    const float* __restrict__ stats_in, float* __restrict__ stats_out,
    const float* resid, float* out_f32, unsigned short* __restrict__ out_bf)
{
  __shared__ __align__(16) float lds[64 * 36];
  const int t = threadIdx.x;
  const int lane = t & 63, wave = t >> 6;
  const int n = blockIdx.x / NSEG;
  const int hw0 = (blockIdx.x % NSEG) * 64;
  const int o_wg = blockIdx.y * 256;

  // staging coords (per-thread constants)
  const int sp = t & 63;
  const int swave = t >> 6;
  const int hw = hw0 + sp;
  const int sh = hw / 56, sw = hw % 56;

  float mean_i = 0.f, rstd_i = 0.f;
  if (PRO != 3) {
    float sm = stats_in[n * 2], sq = stats_in[n * 2 + 1];
    float mn = sm * (1.0f / NELF);
    float vr = sq * (1.0f / NELF) - mn * mn;
    mean_i = mn; rstd_i = rsqrtf(vr + EPS);
  }

  f32x4 acc[4][4];
#pragma unroll
  for (int a = 0; a < 4; ++a)
#pragma unroll
    for (int b = 0; b < 4; ++b) acc[a][b] = (f32x4){0.f, 0.f, 0.f, 0.f};

  const int fr = lane & 15, fq = lane >> 4;

  for (int k0 = 0; k0 < KTOT; k0 += 32) {
    __syncthreads();
    // ---- stage activation tile [64 pix][32 k] as f32 into LDS (stride 36) ----
#pragma unroll
    for (int i = 0; i < 8; ++i) {
      int cl = swave + i * 4;
      int c = k0 + cl;
      float v;
      if (PRO == 0) {
        float raw = act[((size_t)n * KTOT + c) * HW + hw];
        v = (raw - mean_i) * rstd_i * gw[c] + gb[c];
      } else if (PRO == 1) {        // shift along W
        int s = 3 - c / 37;
        int ws_ = sw + s;
        if (ws_ >= 0 && ws_ < 56) {
          float raw = act[((size_t)n * KTOT + c) * HW + sh * 56 + ws_];
          v = geluf((raw - mean_i) * rstd_i * gw[c] + gb[c]);
        } else v = 0.f;
      } else if (PRO == 2) {        // shift along H
        int s = 3 - c / 37;
        int hs = sh + s;
        if (hs >= 0 && hs < 56) {
          float raw = act[((size_t)n * KTOT + c) * HW + hs * 56 + sw];
          v = geluf((raw - mean_i) * rstd_i * gw[c] + gb[c]);
        } else v = 0.f;
      } else {                      // bf16 passthrough (hid)
        v = b2f(act_bf[((size_t)n * KTOT + c) * HW + hw]);
      }
      lds[sp * 36 + cl] = v;
    }
    __syncthreads();

    // ---- fragments ----
    bf16x8 afr[4], bfr[4];
#pragma unroll
    for (int os = 0; os < 4; ++os) {
      const float* wp = Wt + (size_t)(o_wg + wave * 64 + os * 16 + fr) * KTOT + k0 + fq * 8;
      afr[os] = pack8(*(const float4*)wp, *(const float4*)(wp + 4));
    }
#pragma unroll
    for (int ps = 0; ps < 4; ++ps) {
      const float* lp = &lds[(ps * 16 + fr) * 36 + fq * 8];
      bfr[ps] = pack8(*(const float4*)lp, *(const float4*)(lp + 4));
    }
#pragma unroll
    for (int os = 0; os < 4; ++os)
#pragma unroll
      for (int ps = 0; ps < 4; ++ps)
        acc[os][ps] = __builtin_amdgcn_mfma_f32_16x16x32_bf16(afr[os], bfr[ps], acc[os][ps], 0, 0, 0);
  }

  // ---- epilogue ----
  float lsum = 0.f, lsq = 0.f;
#pragma unroll
  for (int os = 0; os < 4; ++os) {
    int ob = o_wg + wave * 64 + os * 16 + fq * 4;
    float4 b4 = *(const float4*)&bias[ob];
    float bb[4] = {b4.x, b4.y, b4.z, b4.w};
#pragma unroll
    for (int ps = 0; ps < 4; ++ps) {
      int pix = hw0 + ps * 16 + fr;
#pragma unroll
      for (int j = 0; j < 4; ++j) {
        size_t oidx = ((size_t)n * OTOT + (ob + j)) * HW + pix;
        float v = acc[os][ps][j] + bb[j];
        if (EPI == 0)      { out_f32[oidx] = v; lsum += v; lsq += v * v; }
        else if (EPI == 1) { out_f32[oidx] = geluf(v); }
        else if (EPI == 2) { float z = out_f32[oidx] + geluf(v); out_f32[oidx] = z; lsum += z; lsq += z * z; }
        else if (EPI == 3) { float z = v + resid[oidx]; out_f32[oidx] = z; lsum += z; lsq += z * z; }
        else if (EPI == 4) { out_bf[oidx] = (unsigned short)f2bf(geluf(v)); }
        else               { out_f32[oidx] = v + resid[oidx]; }
      }
    }
  }

  if (EPI == 0 || EPI == 2 || EPI == 3) {
    __syncthreads();
    lds[t] = lsum; lds[256 + t] = lsq;
    __syncthreads();
    for (int off = 128; off > 0; off >>= 1) {
      if (t < off) { lds[t] += lds[t + off]; lds[256 + t] += lds[256 + t + off]; }
      __syncthreads();
    }
    if (t == 0) { atomicAdd(&stats_out[n * 2], lds[0]); atomicAdd(&stats_out[n * 2 + 1], lds[256]); }
  }
}

extern "C" void kernel_launch(void* const* d_in, const int* in_sizes, int n_in,
                              void* d_out, int out_size, void* d_ws, size_t ws_size,
                              hipStream_t stream) {
  const float* x     = (const float*)d_in[0];
  const float* n1_w  = (const float*)d_in[1];
  const float* n1_b  = (const float*)d_in[2];
  const float* c1_w  = (const float*)d_in[3];
  const float* c1_b  = (const float*)d_in[4];
  const float* an1_w = (const float*)d_in[5];
  const float* an1_b = (const float*)d_in[6];
  const float* c21_w = (const float*)d_in[7];
  const float* c21_b = (const float*)d_in[8];
  const float* c22_w = (const float*)d_in[9];
  const float* c22_b = (const float*)d_in[10];
  const float* an2_w = (const float*)d_in[11];
  const float* an2_b = (const float*)d_in[12];
  const float* c3_w  = (const float*)d_in[13];
  const float* c3_b  = (const float*)d_in[14];
  const float* n2_w  = (const float*)d_in[15];
  const float* n2_b  = (const float*)d_in[16];
  const float* fc1_w = (const float*)d_in[17];
  const float* fc1_b = (const float*)d_in[18];
  const float* fc2_w = (const float*)d_in[19];
  const float* fc2_b = (const float*)d_in[20];

  char* ws = (char*)d_ws;
  float* stats = (float*)ws;                         // 128 floats (4 stat-sets x 16 samples x 2)
  float* ybuf  = (float*)(ws + 4096);                // 51.38 MB f32
  float* zbuf  = (float*)(ws + 4096 + 51380224);     // 51.38 MB f32
  unsigned short* hid = (unsigned short*)(ws + 4096);// 102.76 MB bf16 (reuses y+z after both dead)
  float* out = (float*)d_out;                        // also holds x2 between K3 and K5

  hipMemsetAsync(stats, 0, 512, stream);
  // K0: stats of x
  stats_kernel<<<784, 256, 0, stream>>>(x, stats + 0);
  // K1: y = conv1(gn1(x)); stats(y)
  gemm_kernel<0, 0, 256, 256><<<dim3(784, 1), 256, 0, stream>>>(
      x, nullptr, c1_w, c1_b, n1_w, n1_b, stats + 0, stats + 32, nullptr, ybuf, nullptr);
  // K2a: z = gelu(conv21(shift_w(gelu(gn_as1(y)))))
  gemm_kernel<1, 1, 256, 256><<<dim3(784, 1), 256, 0, stream>>>(
      ybuf, nullptr, c21_w, c21_b, an1_w, an1_b, stats + 32, nullptr, nullptr, zbuf, nullptr);
  // K2b: z += gelu(conv22(shift_h(...))); stats(z)
  gemm_kernel<2, 2, 256, 256><<<dim3(784, 1), 256, 0, stream>>>(
      ybuf, nullptr, c22_w, c22_b, an1_w, an1_b, stats + 32, stats + 64, nullptr, zbuf, nullptr);
  // K3: x2 = x + conv3(gn_as2(z)); stats(x2); x2 -> d_out
  gemm_kernel<0, 3, 256, 256><<<dim3(784, 1), 256, 0, stream>>>(
      zbuf, nullptr, c3_w, c3_b, an2_w, an2_b, stats + 64, stats + 96, x, out, nullptr);
  // K4: hid = gelu(fc1(gn2(x2)))  (bf16)
  gemm_kernel<0, 4, 256, 1024><<<dim3(784, 4), 256, 0, stream>>>(
      out, nullptr, fc1_w, fc1_b, n2_w, n2_b, stats + 96, nullptr, nullptr, nullptr, hid);
  // K5: out = x2 + fc2(hid)
  gemm_kernel<3, 5, 1024, 256><<<dim3(784, 1), 256, 0, stream>>>(
      nullptr, hid, fc2_w, fc2_b, nullptr, nullptr, nullptr, nullptr, out, out, nullptr);
}

// Round 2
// 407.790 us; speedup vs baseline: 1.8612x; 1.8612x over previous
//
#include <hip/hip_runtime.h>

typedef __attribute__((ext_vector_type(4))) float f32x4;
typedef __attribute__((ext_vector_type(8))) short bf16x8;
typedef __attribute__((ext_vector_type(4))) unsigned short u16x4;
typedef unsigned short u16;

#define HW 3136
#define NSEG 49            // 3136/64 pixel tiles per sample
#define NELF 802816.0f     // 256*3136
#define EPS 1e-5f

__device__ __forceinline__ float geluf(float x) {
  return 0.5f * x * (1.0f + erff(x * 0.70710678118654752440f));
}
__device__ __forceinline__ short f2bf(float f) {
  union { float f; unsigned u; } v; v.f = f;
  unsigned r = (v.u + 0x7FFFu + ((v.u >> 16) & 1u)) >> 16;
  return (short)r;
}
__device__ __forceinline__ float b2f(u16 u) {
  union { unsigned u; float f; } v; v.u = ((unsigned)u) << 16;
  return v.f;
}

// ---- W0: convert all six weight matrices f32 -> bf16 into ws ----
__global__ void wconv_kernel(const float* __restrict__ c1, const float* __restrict__ c21,
                             const float* __restrict__ c22, const float* __restrict__ c3,
                             const float* __restrict__ fc1, const float* __restrict__ fc2,
                             u16* __restrict__ out) {
  int i = (blockIdx.x * 256 + threadIdx.x) * 4;   // 768 blocks -> 786432 elems
  const float* src; int off;
  if (i < 65536)       { src = c1;  off = 0; }
  else if (i < 131072) { src = c21; off = 65536; }
  else if (i < 196608) { src = c22; off = 131072; }
  else if (i < 262144) { src = c3;  off = 196608; }
  else if (i < 524288) { src = fc1; off = 262144; }
  else                 { src = fc2; off = 524288; }
  float4 v = *(const float4*)(src + (i - off));
  u16x4 o; o[0] = (u16)f2bf(v.x); o[1] = (u16)f2bf(v.y); o[2] = (u16)f2bf(v.z); o[3] = (u16)f2bf(v.w);
  *(u16x4*)(out + i) = o;
}

// ---- K0: per-sample sum/sumsq of x ----
__global__ void stats_kernel(const float* __restrict__ x, float* __restrict__ st) {
  int b = blockIdx.x, t = threadIdx.x;
  int n = b / NSEG, seg = b % NSEG;
  const float* p = x + (size_t)n * 802816 + (size_t)seg * 16384;
  float s = 0.f, q = 0.f;
#pragma unroll
  for (int i = 0; i < 16; ++i) {
    float4 v = *(const float4*)(p + (size_t)(t + i * 256) * 4);
    s += v.x + v.y + v.z + v.w;
    q += v.x * v.x + v.y * v.y + v.z * v.z + v.w * v.w;
  }
  __shared__ float r[512];
  r[t] = s; r[256 + t] = q;
  __syncthreads();
  for (int off = 128; off > 0; off >>= 1) {
    if (t < off) { r[t] += r[t + off]; r[256 + t] += r[256 + t + off]; }
    __syncthreads();
  }
  if (t == 0) { atomicAdd(&st[n * 2], r[0]); atomicAdd(&st[n * 2 + 1], r[256]); }
}

// ---- E2: t = bf16(gelu(gn_as1(y))) elementwise ----
__global__ void e2_kernel(const u16* __restrict__ y, u16* __restrict__ t,
                          const float* __restrict__ gw, const float* __restrict__ gb,
                          const float* __restrict__ stats) {
  const size_t NG = (size_t)16 * 256 * 392;  // ushort8 groups (rows divide evenly)
  for (size_t g = (size_t)blockIdx.x * blockDim.x + threadIdx.x; g < NG;
       g += (size_t)gridDim.x * blockDim.x) {
    size_t base = g * 8;
    int n = (int)(base / 802816);
    int c = (int)((base / HW) & 255);
    float sm = stats[n * 2], sq = stats[n * 2 + 1];
    float mn = sm * (1.0f / NELF);
    float rstd = rsqrtf(sq * (1.0f / NELF) - mn * mn + EPS);
    float scale = rstd * gw[c];
    float shift = gb[c] - mn * scale;
    bf16x8 v = *(const bf16x8*)(y + base);
    bf16x8 o;
#pragma unroll
    for (int j = 0; j < 8; ++j) o[j] = f2bf(geluf(b2f((u16)v[j]) * scale + shift));
    *(bf16x8*)(t + base) = o;
  }
}

// ---- main GEMM ----
// PRO: 0 = f32 act + GN; 1 = bf16 act + GN; 2 = bf16 passthrough
// EPI: 0 = store bf16 + stats; 1 = +resid store f32 + stats; 2 = gelu store bf16; 3 = +resid store f32
template<int PRO, int EPI, int KTOT, int OTOT>
__global__ __launch_bounds__(256, 3) void gemm2(
    const void* __restrict__ act, const u16* __restrict__ wt,
    const float* __restrict__ bias, const float* __restrict__ gw, const float* __restrict__ gb,
    const float* __restrict__ stats_in, float* __restrict__ stats_out,
    const float* __restrict__ resid, float* __restrict__ out_f32, u16* __restrict__ out_bf)
{
  __shared__ __align__(16) u16 tile[64 * 40];
  const int t = threadIdx.x;
  const int lane = t & 63;
  const int sp = t & 63, sw = t >> 6;
  const int n = blockIdx.x / NSEG;
  const int hw0 = (blockIdx.x % NSEG) * 64;
  const int obase = blockIdx.y * 256 + (t >> 6) * 64;
  const int hw = hw0 + sp;
  const int fr = lane & 15, fq = lane >> 4;

  float mean = 0.f, rstd = 0.f;
  if (PRO != 2) {
    float sm = stats_in[n * 2], sq = stats_in[n * 2 + 1];
    mean = sm * (1.0f / NELF);
    rstd = rsqrtf(sq * (1.0f / NELF) - mean * mean + EPS);
  }

  f32x4 acc[4][4];
#pragma unroll
  for (int a = 0; a < 4; ++a)
#pragma unroll
    for (int b = 0; b < 4; ++b) acc[a][b] = (f32x4){0.f, 0.f, 0.f, 0.f};

  for (int k0 = 0; k0 < KTOT; k0 += 32) {
    __syncthreads();
    {
      bf16x8 st;
      const int cbase = k0 + sw * 8;
#pragma unroll
      for (int j = 0; j < 8; ++j) {
        int c = cbase + j;
        if (PRO == 0) {
          float raw = ((const float*)act)[((size_t)n * KTOT + c) * HW + hw];
          st[j] = f2bf((raw - mean) * rstd * gw[c] + gb[c]);
        } else if (PRO == 1) {
          float raw = b2f(((const u16*)act)[((size_t)n * KTOT + c) * HW + hw]);
          st[j] = f2bf((raw - mean) * rstd * gw[c] + gb[c]);
        } else {
          st[j] = (short)((const u16*)act)[((size_t)n * KTOT + c) * HW + hw];
        }
      }
      *(bf16x8*)&tile[sp * 40 + sw * 8] = st;
    }
    __syncthreads();

    bf16x8 bfr[4];
#pragma unroll
    for (int ps = 0; ps < 4; ++ps)
      bfr[ps] = *(const bf16x8*)&tile[(ps * 16 + fr) * 40 + fq * 8];
#pragma unroll
    for (int os = 0; os < 4; ++os) {
      bf16x8 afr = *(const bf16x8*)&wt[(size_t)(obase + os * 16 + fr) * KTOT + k0 + fq * 8];
#pragma unroll
      for (int ps = 0; ps < 4; ++ps)
        acc[os][ps] = __builtin_amdgcn_mfma_f32_16x16x32_bf16(afr, bfr[ps], acc[os][ps], 0, 0, 0);
    }
  }

  float lsum = 0.f, lsq = 0.f;
#pragma unroll
  for (int os = 0; os < 4; ++os) {
    int ob = obase + os * 16 + fq * 4;
    float4 b4 = *(const float4*)&bias[ob];
    float bb[4] = {b4.x, b4.y, b4.z, b4.w};
#pragma unroll
    for (int ps = 0; ps < 4; ++ps) {
      int pix = hw0 + ps * 16 + fr;
#pragma unroll
      for (int j = 0; j < 4; ++j) {
        size_t oidx = ((size_t)n * OTOT + (ob + j)) * HW + pix;
        float v = acc[os][ps][j] + bb[j];
        if (EPI == 0)      { out_bf[oidx] = (u16)f2bf(v); lsum += v; lsq += v * v; }
        else if (EPI == 1) { float z = v + resid[oidx]; out_f32[oidx] = z; lsum += z; lsq += z * z; }
        else if (EPI == 2) { out_bf[oidx] = (u16)f2bf(geluf(v)); }
        else               { out_f32[oidx] = v + resid[oidx]; }
      }
    }
  }

  if (EPI == 0 || EPI == 1) {
    float* red = (float*)tile;
    __syncthreads();
    red[t] = lsum; red[256 + t] = lsq;
    __syncthreads();
    for (int off = 128; off > 0; off >>= 1) {
      if (t < off) { red[t] += red[t + off]; red[256 + t] += red[256 + t + off]; }
      __syncthreads();
    }
    if (t == 0) { atomicAdd(&stats_out[n * 2], red[0]); atomicAdd(&stats_out[n * 2 + 1], red[256]); }
  }
}

// ---- G2: dual shifted GEMM  z = gelu(conv21(shift_w(t))) + gelu(conv22(shift_h(t))) ----
__global__ __launch_bounds__(256, 2) void gemm_dual(
    const u16* __restrict__ tact, const u16* __restrict__ wA, const u16* __restrict__ wB,
    const float* __restrict__ biasA, const float* __restrict__ biasB,
    float* __restrict__ stats_out, u16* __restrict__ zout)
{
  __shared__ __align__(16) u16 tA[64 * 40];
  __shared__ __align__(16) u16 tB[64 * 40];
  const int t = threadIdx.x;
  const int lane = t & 63;
  const int sp = t & 63, sw = t >> 6;
  const int n = blockIdx.x / NSEG;
  const int hw0 = (blockIdx.x % NSEG) * 64;
  const int obase = (t >> 6) * 64;
  const int hw = hw0 + sp;
  const int shp = hw / 56, swp = hw % 56;
  const int fr = lane & 15, fq = lane >> 4;

  f32x4 accA[4][4], accB[4][4];
#pragma unroll
  for (int a = 0; a < 4; ++a)
#pragma unroll
    for (int b = 0; b < 4; ++b) { accA[a][b] = (f32x4){0,0,0,0}; accB[a][b] = (f32x4){0,0,0,0}; }

  const size_t nb = (size_t)n * 256;
  for (int k0 = 0; k0 < 256; k0 += 32) {
    __syncthreads();
    {
      bf16x8 sA, sB;
      const int cbase = k0 + sw * 8;
#pragma unroll
      for (int j = 0; j < 8; ++j) {
        int c = cbase + j;
        int s = 3 - c / 37;
        const u16* row = tact + (nb + c) * HW;
        int fa = hw + s;
        fa = fa < 0 ? 0 : (fa > HW - 1 ? HW - 1 : fa);
        u16 ua = row[fa];
        sA[j] = ((unsigned)(swp + s) < 56u) ? (short)ua : (short)0;
        int fb = hw + 56 * s;
        fb = fb < 0 ? 0 : (fb > HW - 1 ? HW - 1 : fb);
        u16 ub = row[fb];
        sB[j] = ((unsigned)(shp + s) < 56u) ? (short)ub : (short)0;
      }
      *(bf16x8*)&tA[sp * 40 + sw * 8] = sA;
      *(bf16x8*)&tB[sp * 40 + sw * 8] = sB;
    }
    __syncthreads();

    bf16x8 bfrA[4], bfrB[4];
#pragma unroll
    for (int ps = 0; ps < 4; ++ps) {
      bfrA[ps] = *(const bf16x8*)&tA[(ps * 16 + fr) * 40 + fq * 8];
      bfrB[ps] = *(const bf16x8*)&tB[(ps * 16 + fr) * 40 + fq * 8];
    }
#pragma unroll
    for (int os = 0; os < 4; ++os) {
      bf16x8 afrA = *(const bf16x8*)&wA[(size_t)(obase + os * 16 + fr) * 256 + k0 + fq * 8];
      bf16x8 afrB = *(const bf16x8*)&wB[(size_t)(obase + os * 16 + fr) * 256 + k0 + fq * 8];
#pragma unroll
      for (int ps = 0; ps < 4; ++ps) {
        accA[os][ps] = __builtin_amdgcn_mfma_f32_16x16x32_bf16(afrA, bfrA[ps], accA[os][ps], 0, 0, 0);
        accB[os][ps] = __builtin_amdgcn_mfma_f32_16x16x32_bf16(afrB, bfrB[ps], accB[os][ps], 0, 0, 0);
      }
    }
  }

  float lsum = 0.f, lsq = 0.f;
#pragma unroll
  for (int os = 0; os < 4; ++os) {
    int ob = obase + os * 16 + fq * 4;
    float4 a4 = *(const float4*)&biasA[ob];
    float4 b4 = *(const float4*)&biasB[ob];
    float ba[4] = {a4.x, a4.y, a4.z, a4.w};
    float bb[4] = {b4.x, b4.y, b4.z, b4.w};
#pragma unroll
    for (int ps = 0; ps < 4; ++ps) {
      int pix = hw0 + ps * 16 + fr;
#pragma unroll
      for (int j = 0; j < 4; ++j) {
        size_t oidx = ((size_t)n * 256 + (ob + j)) * HW + pix;
        float z = geluf(accA[os][ps][j] + ba[j]) + geluf(accB[os][ps][j] + bb[j]);
        zout[oidx] = (u16)f2bf(z);
        lsum += z; lsq += z * z;
      }
    }
  }

  float* red = (float*)tA;
  __syncthreads();
  red[t] = lsum; red[256 + t] = lsq;
  __syncthreads();
  for (int off = 128; off > 0; off >>= 1) {
    if (t < off) { red[t] += red[t + off]; red[256 + t] += red[256 + t + off]; }
    __syncthreads();
  }
  if (t == 0) { atomicAdd(&stats_out[n * 2], red[0]); atomicAdd(&stats_out[n * 2 + 1], red[256]); }
}

extern "C" void kernel_launch(void* const* d_in, const int* in_sizes, int n_in,
                              void* d_out, int out_size, void* d_ws, size_t ws_size,
                              hipStream_t stream) {
  const float* x     = (const float*)d_in[0];
  const float* n1_w  = (const float*)d_in[1];
  const float* n1_b  = (const float*)d_in[2];
  const float* c1_w  = (const float*)d_in[3];
  const float* c1_b  = (const float*)d_in[4];
  const float* an1_w = (const float*)d_in[5];
  const float* an1_b = (const float*)d_in[6];
  const float* c21_w = (const float*)d_in[7];
  const float* c21_b = (const float*)d_in[8];
  const float* c22_w = (const float*)d_in[9];
  const float* c22_b = (const float*)d_in[10];
  const float* an2_w = (const float*)d_in[11];
  const float* an2_b = (const float*)d_in[12];
  const float* c3_w  = (const float*)d_in[13];
  const float* c3_b  = (const float*)d_in[14];
  const float* n2_w  = (const float*)d_in[15];
  const float* n2_b  = (const float*)d_in[16];
  const float* fc1_w = (const float*)d_in[17];
  const float* fc1_b = (const float*)d_in[18];
  const float* fc2_w = (const float*)d_in[19];
  const float* fc2_b = (const float*)d_in[20];

  char* ws = (char*)d_ws;
  float* stats = (float*)ws;                       // 512 B: x, y, z, x2 stat-sets
  u16* wbuf = (u16*)(ws + 1024);                   // 1.57 MB bf16 weights
  u16* wb_c1  = wbuf;
  u16* wb_c21 = wbuf + 65536;
  u16* wb_c22 = wbuf + 131072;
  u16* wb_c3  = wbuf + 196608;
  u16* wb_fc1 = wbuf + 262144;
  u16* wb_fc2 = wbuf + 524288;
  const size_t ABUF = 25690112;                    // 16*256*3136*2 bytes
  char* A0 = ws + 1024 + 1572864;
  u16* ybuf = (u16*)(A0);
  u16* tbuf = (u16*)(A0 + ABUF);
  u16* zbuf = (u16*)(A0 + 2 * ABUF);
  u16* hid  = (u16*)(A0);                          // 102.76 MB, overlaps y/t/z (dead by G4)
  float* out = (float*)d_out;                      // holds x2 after G3

  hipMemsetAsync(stats, 0, 512, stream);
  wconv_kernel<<<768, 256, 0, stream>>>(c1_w, c21_w, c22_w, c3_w, fc1_w, fc2_w, wbuf);
  stats_kernel<<<784, 256, 0, stream>>>(x, stats + 0);
  // G1: y = conv1(gn1(x)) -> bf16, stats(y)
  gemm2<0, 0, 256, 256><<<dim3(784, 1), 256, 0, stream>>>(
      x, wb_c1, c1_b, n1_w, n1_b, stats + 0, stats + 32, nullptr, nullptr, ybuf);
  // E2: t = gelu(gn_as1(y))
  e2_kernel<<<2048, 256, 0, stream>>>(ybuf, tbuf, an1_w, an1_b, stats + 32);
  // G2: z = gelu(conv21(shift_w(t))) + gelu(conv22(shift_h(t))), stats(z)
  gemm_dual<<<784, 256, 0, stream>>>(tbuf, wb_c21, wb_c22, c21_b, c22_b, stats + 64, zbuf);
  // G3: x2 = x + conv3(gn_as2(z)) -> d_out f32, stats(x2)
  gemm2<1, 1, 256, 256><<<dim3(784, 1), 256, 0, stream>>>(
      zbuf, wb_c3, c3_b, an2_w, an2_b, stats + 64, stats + 96, x, out, nullptr);
  // G4: hid = gelu(fc1(gn2(x2))) -> bf16
  gemm2<0, 2, 256, 1024><<<dim3(784, 4), 256, 0, stream>>>(
      out, wb_fc1, fc1_b, n2_w, n2_b, stats + 96, nullptr, nullptr, nullptr, hid);
  // G5: out = x2 + fc2(hid)
  gemm2<2, 3, 1024, 256><<<dim3(784, 1), 256, 0, stream>>>(
      hid, wb_fc2, fc2_b, nullptr, nullptr, nullptr, nullptr, out, out, nullptr);
}